// Round 1
// baseline (365.660 us; speedup 1.0000x reference)
//
#include <hip/hip_runtime.h>
#include <hip/hip_bf16.h>

#define NB 2
#define C_IN 64
#define N_SP 32768
#define NHEADS 4
#define DH 32
#define HID 128
#define QK_SCALE 0.17677669529663687f  // 32^-0.5
#define NCH 16                          // chunks per (b,h) in K2
#define CL (N_SP / NCH)                 // 2048
#define TILE 128
#define GN_EPS_C 1e-5f

// ---------------- K1: qkv = w_qkv @ x, q-softmax, store bf16 ----------------
__global__ __launch_bounds__(256) void k1_qkv(const float* __restrict__ x,
        const float* __restrict__ wqkv,
        __hip_bfloat16* __restrict__ qs, __hip_bfloat16* __restrict__ ke,
        __hip_bfloat16* __restrict__ vv) {
    int t = threadIdx.x;
    int h = t >> 6;                    // wave-uniform head
    int p = blockIdx.x * 64 + (t & 63);
    int b = p >> 15;
    int nn = p & (N_SP - 1);
    const float* xp = x + (size_t)b * C_IN * N_SP + nn;
    float xr[64];
#pragma unroll
    for (int c = 0; c < 64; ++c) xr[c] = xp[(size_t)c * N_SP];

    size_t obase = (size_t)b * HID * N_SP + (size_t)h * DH * N_SP + nn;

    // --- q rows (h*32 .. h*32+31), softmax over the 32 dims ---
    {
        const float* wq = wqkv + (size_t)h * DH * 64;
        float acc[DH];
#pragma unroll
        for (int d = 0; d < DH; ++d) {
            float a = 0.f;
#pragma unroll
            for (int c = 0; c < 64; ++c) a = fmaf(wq[d * 64 + c], xr[c], a);
            acc[d] = a;
        }
        float m = acc[0];
#pragma unroll
        for (int d = 1; d < DH; ++d) m = fmaxf(m, acc[d]);
        float s = 0.f;
#pragma unroll
        for (int d = 0; d < DH; ++d) { acc[d] = __expf(acc[d] - m); s += acc[d]; }
        float inv = QK_SCALE / s;
#pragma unroll
        for (int d = 0; d < DH; ++d)
            qs[obase + (size_t)d * N_SP] = __float2bfloat16(acc[d] * inv);
    }
    // --- k rows (128 + h*32 ..): store exp(k) (softmax denom handled later) ---
    {
        const float* wk = wqkv + (size_t)(HID + h * DH) * 64;
#pragma unroll 4
        for (int d = 0; d < DH; ++d) {
            float a = 0.f;
#pragma unroll
            for (int c = 0; c < 64; ++c) a = fmaf(wk[d * 64 + c], xr[c], a);
            ke[obase + (size_t)d * N_SP] = __float2bfloat16(__expf(a));
        }
    }
    // --- v rows (256 + h*32 ..) ---
    {
        const float* wv = wqkv + (size_t)(2 * HID + h * DH) * 64;
#pragma unroll 4
        for (int d = 0; d < DH; ++d) {
            float a = 0.f;
#pragma unroll
            for (int c = 0; c < 64; ++c) a = fmaf(wv[d * 64 + c], xr[c], a);
            vv[obase + (size_t)d * N_SP] = __float2bfloat16(a);
        }
    }
}

// ------------- K2: partial context[d][e] = sum_n exp(k)[d,n]*v[e,n] ---------
__global__ __launch_bounds__(256) void k2_ctx_part(const __hip_bfloat16* __restrict__ ke,
        const __hip_bfloat16* __restrict__ vv,
        float* __restrict__ ctx_part, float* __restrict__ ksum_part) {
    __shared__ float lk[DH * (TILE + 1)];
    __shared__ float lv[DH * (TILE + 1)];
    int bh = blockIdx.x / NCH;
    int ch = blockIdx.x % NCH;
    int b = bh >> 2, h = bh & 3;
    size_t base = (size_t)b * HID * N_SP + (size_t)h * DH * N_SP + (size_t)ch * CL;
    int t = threadIdx.x;
    int d = t >> 3, eg = t & 7;
    float a0 = 0, a1 = 0, a2 = 0, a3 = 0, ks = 0;
    for (int tile = 0; tile < CL / TILE; ++tile) {
        size_t tb = base + (size_t)tile * TILE;
        __syncthreads();
#pragma unroll
        for (int i = 0; i < (DH * TILE) / 256; ++i) {
            int idx = t + i * 256;
            int r = idx >> 7, cc = idx & (TILE - 1);
            lk[r * (TILE + 1) + cc] = __bfloat162float(ke[tb + (size_t)r * N_SP + cc]);
            lv[r * (TILE + 1) + cc] = __bfloat162float(vv[tb + (size_t)r * N_SP + cc]);
        }
        __syncthreads();
        for (int pos = 0; pos < TILE; ++pos) {
            float kd = lk[d * (TILE + 1) + pos];
            ks += kd;
            a0 = fmaf(kd, lv[(eg * 4 + 0) * (TILE + 1) + pos], a0);
            a1 = fmaf(kd, lv[(eg * 4 + 1) * (TILE + 1) + pos], a1);
            a2 = fmaf(kd, lv[(eg * 4 + 2) * (TILE + 1) + pos], a2);
            a3 = fmaf(kd, lv[(eg * 4 + 3) * (TILE + 1) + pos], a3);
        }
    }
    float* cp = ctx_part + (size_t)blockIdx.x * 1024 + d * 32 + eg * 4;
    cp[0] = a0; cp[1] = a1; cp[2] = a2; cp[3] = a3;
    if (eg == 0) ksum_part[blockIdx.x * 32 + d] = ks;
}

// ------------- K3: reduce partials, divide by k-softmax denominator ---------
__global__ __launch_bounds__(1024) void k3_ctx_reduce(const float* __restrict__ ctx_part,
        const float* __restrict__ ksum_part, float* __restrict__ ctx) {
    int bh = blockIdx.x;
    int t = threadIdx.x;  // d*32+e
    __shared__ float kst[DH];
    if (t < DH) {
        float s = 0.f;
        for (int ch = 0; ch < NCH; ++ch)
            s += ksum_part[(bh * NCH + ch) * 32 + t];
        kst[t] = s;
    }
    __syncthreads();
    float s = 0.f;
    for (int ch = 0; ch < NCH; ++ch)
        s += ctx_part[(size_t)(bh * NCH + ch) * 1024 + t];
    ctx[bh * 1024 + t] = s / kst[t >> 5];
}

// ------- K4: out = ctx^T q ; y = w_out@out + b ; stats partials ------------
__global__ __launch_bounds__(256) void k4_out(const __hip_bfloat16* __restrict__ qs,
        const float* __restrict__ ctx, const float* __restrict__ wout,
        const float* __restrict__ bout, float* __restrict__ y,
        float* __restrict__ part_stats) {
    __shared__ float ctx_l[NHEADS * 1024];
    __shared__ float red[8];
    int t = threadIdx.x;
    int p = blockIdx.x * 256 + t;
    int b = p >> 15, nn = p & (N_SP - 1);
#pragma unroll
    for (int i = 0; i < 16; ++i) ctx_l[t + i * 256] = ctx[b * 4096 + t + i * 256];
    __syncthreads();
    float ya[64];
#pragma unroll
    for (int o = 0; o < 64; ++o) ya[o] = 0.f;
    for (int h = 0; h < NHEADS; ++h) {
        float qr[DH];
        size_t qb = (size_t)b * HID * N_SP + (size_t)h * DH * N_SP + nn;
#pragma unroll
        for (int d = 0; d < DH; ++d) qr[d] = __bfloat162float(qs[qb + (size_t)d * N_SP]);
        for (int e = 0; e < DH; ++e) {
            float oe = 0.f;
#pragma unroll
            for (int d = 0; d < DH; ++d) oe = fmaf(ctx_l[h * 1024 + d * 32 + e], qr[d], oe);
            const float* wo = wout + h * DH + e;
#pragma unroll
            for (int o = 0; o < 64; ++o) ya[o] = fmaf(wo[o * HID], oe, ya[o]);
        }
    }
    float s = 0.f, s2 = 0.f;
    size_t yb = (size_t)b * C_IN * N_SP + nn;
#pragma unroll
    for (int o = 0; o < 64; ++o) {
        float v = ya[o] + bout[o];
        y[yb + (size_t)o * N_SP] = v;
        s += v;
        s2 = fmaf(v, v, s2);
    }
#pragma unroll
    for (int off = 32; off > 0; off >>= 1) {
        s += __shfl_down(s, off, 64);
        s2 += __shfl_down(s2, off, 64);
    }
    int wid = t >> 6;
    if ((t & 63) == 0) { red[wid * 2] = s; red[wid * 2 + 1] = s2; }
    __syncthreads();
    if (t == 0) {
        part_stats[blockIdx.x * 2]     = red[0] + red[2] + red[4] + red[6];
        part_stats[blockIdx.x * 2 + 1] = red[1] + red[3] + red[5] + red[7];
    }
}

// ------------- K4b: finalize per-batch mean/var inputs (deterministic) ------
__global__ __launch_bounds__(128) void k4b_stats(const float* __restrict__ part_stats,
        float* __restrict__ stats) {
    int batch = blockIdx.x;
    int t = threadIdx.x;  // 128 K4-blocks per batch
    float s  = part_stats[(batch * 128 + t) * 2];
    float s2 = part_stats[(batch * 128 + t) * 2 + 1];
#pragma unroll
    for (int off = 32; off > 0; off >>= 1) {
        s += __shfl_down(s, off, 64);
        s2 += __shfl_down(s2, off, 64);
    }
    __shared__ float red[4];
    if ((t & 63) == 0) { red[(t >> 6) * 2] = s; red[(t >> 6) * 2 + 1] = s2; }
    __syncthreads();
    if (t == 0) {
        stats[batch * 2]     = red[0] + red[2];
        stats[batch * 2 + 1] = red[1] + red[3];
    }
}

// ---------------------------- K5: apply GroupNorm ---------------------------
__global__ __launch_bounds__(256) void k5_gn(const float* __restrict__ y,
        const float* __restrict__ stats, const float* __restrict__ gnw,
        const float* __restrict__ gnb, float* __restrict__ out) {
    int gid = blockIdx.x * 256 + threadIdx.x;  // float4 index
    size_t base = (size_t)gid * 4;
    int b = (int)(base >> 21);          // 64*32768 = 2^21 per batch
    int o = (int)((base >> 15) & 63);
    const float NGN = 64.f * 32768.f;
    float mean = stats[b * 2] / NGN;
    float var  = stats[b * 2 + 1] / NGN - mean * mean;
    float inv  = rsqrtf(var + GN_EPS_C);
    float w  = gnw[o] * inv;
    float bb = gnb[o] - mean * inv * gnw[o];
    float4 v = reinterpret_cast<const float4*>(y)[gid];
    float4 r;
    r.x = fmaf(v.x, w, bb);
    r.y = fmaf(v.y, w, bb);
    r.z = fmaf(v.z, w, bb);
    r.w = fmaf(v.w, w, bb);
    reinterpret_cast<float4*>(out)[gid] = r;
}

extern "C" void kernel_launch(void* const* d_in, const int* in_sizes, int n_in,
                              void* d_out, int out_size, void* d_ws, size_t ws_size,
                              hipStream_t stream) {
    const float* x    = (const float*)d_in[0];
    const float* wqkv = (const float*)d_in[1];
    const float* wout = (const float*)d_in[2];
    const float* bout = (const float*)d_in[3];
    const float* gnw  = (const float*)d_in[4];
    const float* gnb  = (const float*)d_in[5];
    float* out = (float*)d_out;

    char* ws = (char*)d_ws;
    const size_t QKV_ELEMS = (size_t)NB * HID * N_SP;        // 8,388,608
    __hip_bfloat16* qs = (__hip_bfloat16*)(ws);
    __hip_bfloat16* ke = (__hip_bfloat16*)(ws + QKV_ELEMS * 2);
    __hip_bfloat16* vv = (__hip_bfloat16*)(ws + QKV_ELEMS * 4);
    float* y          = (float*)(ws + QKV_ELEMS * 6);                       // 16 MB
    float* ctx_part   = (float*)(ws + QKV_ELEMS * 6 + 16777216);            // 512 KB
    float* ksum_part  = (float*)(ws + QKV_ELEMS * 6 + 16777216 + 524288);   // 16 KB
    float* ctx        = (float*)(ws + QKV_ELEMS * 6 + 16777216 + 540672);   // 32 KB
    float* part_stats = (float*)(ws + QKV_ELEMS * 6 + 16777216 + 573440);   // 2 KB
    float* stats      = (float*)(ws + QKV_ELEMS * 6 + 16777216 + 575488);   // 16 B

    k1_qkv<<<dim3(1024), dim3(256), 0, stream>>>(x, wqkv, qs, ke, vv);
    k2_ctx_part<<<dim3(NB * NHEADS * NCH), dim3(256), 0, stream>>>(ke, vv, ctx_part, ksum_part);
    k3_ctx_reduce<<<dim3(NB * NHEADS), dim3(1024), 0, stream>>>(ctx_part, ksum_part, ctx);
    k4_out<<<dim3(256), dim3(256), 0, stream>>>(qs, ctx, wout, bout, y, part_stats);
    k4b_stats<<<dim3(NB), dim3(128), 0, stream>>>(part_stats, stats);
    k5_gn<<<dim3(4096), dim3(256), 0, stream>>>(y, stats, gnw, gnb, out);
}

// Round 2
// 65.235 us; speedup vs baseline: 5.6053x; 5.6053x over previous
//
#include <hip/hip_runtime.h>
#include <hip/hip_bf16.h>

#define NB 2
#define C_IN 64
#define N_SP 32768
#define NHEADS 4
#define DH 32
#define HID 128
#define QK_SCALE 0.17677669529663687f  // 32^-0.5
#define GN_EPS_C 1e-5f
#define NCH2 64
#define CL2 (N_SP / NCH2)  // 512

using bf16x8 = __attribute__((ext_vector_type(8))) short;
using f32x4  = __attribute__((ext_vector_type(4))) float;
using u16x8  = __attribute__((ext_vector_type(8))) unsigned short;

__device__ __forceinline__ unsigned short f2bf(float f) {
    union { float f; unsigned u; } c{f};
    unsigned r = c.u + 0x7FFFu + ((c.u >> 16) & 1u);   // RNE
    return (unsigned short)(r >> 16);
}
__device__ __forceinline__ float bf2f(unsigned short u) {
    union { unsigned u; float f; } c{ (unsigned)u << 16 };
    return c.f;
}

// ============ K1: qkv = w_qkv @ x (MFMA), fused q-softmax / exp(k) ==========
__global__ __launch_bounds__(256) void k1_qkv(const float* __restrict__ x,
        const float* __restrict__ wqkv, unsigned short* __restrict__ qs,
        unsigned short* __restrict__ ke, unsigned short* __restrict__ vv) {
    __shared__ unsigned short wl[384 * 64];  // 48 KB bf16, XOR-swizzled
    int t = threadIdx.x;
    // stage weights fp32 -> bf16 into LDS (swizzle: byte ^= (row&7)<<4)
    for (int i = 0; i < 12; ++i) {
        int chunk = t + i * 256;            // 0..3071
        int row = chunk >> 3, c8 = (chunk & 7) * 8;
        const float* wp = wqkv + row * 64 + c8;
        bf16x8 w;
#pragma unroll
        for (int j = 0; j < 8; ++j) w[j] = (short)f2bf(wp[j]);
        int baddr = (row * 128 + c8 * 2) ^ ((row & 7) << 4);
        *(bf16x8*)((char*)wl + baddr) = w;
    }
    __syncthreads();

    int wv = t >> 6, l = t & 63, lg = l >> 4, lc = l & 15;
    int p0 = blockIdx.x * 256 + wv * 64;
    int b = p0 >> 15, n0 = p0 & (N_SP - 1);
    const float* xb = x + (size_t)b * C_IN * N_SP;

    // B fragments: x columns for this wave's 64 positions
    bf16x8 bfrag[4][2];
#pragma unroll
    for (int s = 0; s < 4; ++s) {
        int n = n0 + s * 16 + lc;
#pragma unroll
        for (int kk = 0; kk < 2; ++kk) {
            bf16x8 v;
#pragma unroll
            for (int j = 0; j < 8; ++j) {
                int c = kk * 32 + lg * 8 + j;
                v[j] = (short)f2bf(xb[(size_t)c * N_SP + n]);
            }
            bfrag[s][kk] = v;
        }
    }

    size_t obase = (size_t)b * HID * N_SP + n0;

    // ---- q: mtiles 0..7, per head softmax over 32 rows ----
#pragma unroll
    for (int h = 0; h < NHEADS; ++h) {
        f32x4 acc[2][4] = {};
#pragma unroll
        for (int mi = 0; mi < 2; ++mi) {
            int row0 = (2 * h + mi) * 16;
#pragma unroll
            for (int kk = 0; kk < 2; ++kk) {
                int row = row0 + lc;
                int baddr = (row * 128 + (kk * 32 + lg * 8) * 2) ^ ((row & 7) << 4);
                bf16x8 a = *(const bf16x8*)((const char*)wl + baddr);
#pragma unroll
                for (int s = 0; s < 4; ++s)
                    acc[mi][s] = __builtin_amdgcn_mfma_f32_16x16x32_bf16(a, bfrag[s][kk], acc[mi][s], 0, 0, 0);
            }
        }
#pragma unroll
        for (int s = 0; s < 4; ++s) {
            float m = -1e30f;
#pragma unroll
            for (int mi = 0; mi < 2; ++mi)
#pragma unroll
                for (int r = 0; r < 4; ++r) m = fmaxf(m, acc[mi][s][r]);
            m = fmaxf(m, __shfl_xor(m, 16));
            m = fmaxf(m, __shfl_xor(m, 32));
            float sum = 0.f;
#pragma unroll
            for (int mi = 0; mi < 2; ++mi)
#pragma unroll
                for (int r = 0; r < 4; ++r) {
                    float e = __expf(acc[mi][s][r] - m);
                    acc[mi][s][r] = e; sum += e;
                }
            sum += __shfl_xor(sum, 16);
            sum += __shfl_xor(sum, 32);
            float inv = QK_SCALE / sum;
#pragma unroll
            for (int mi = 0; mi < 2; ++mi)
#pragma unroll
                for (int r = 0; r < 4; ++r) {
                    int o = h * 32 + mi * 16 + lg * 4 + r;
                    qs[obase + (size_t)o * N_SP + s * 16 + lc] = f2bf(acc[mi][s][r] * inv);
                }
        }
    }
    // ---- k: mtiles 8..15, store exp(k) ----
#pragma unroll
    for (int g = 0; g < 4; ++g) {
        f32x4 acc[2][4] = {};
#pragma unroll
        for (int mi = 0; mi < 2; ++mi) {
            int row0 = (8 + 2 * g + mi) * 16;
#pragma unroll
            for (int kk = 0; kk < 2; ++kk) {
                int row = row0 + lc;
                int baddr = (row * 128 + (kk * 32 + lg * 8) * 2) ^ ((row & 7) << 4);
                bf16x8 a = *(const bf16x8*)((const char*)wl + baddr);
#pragma unroll
                for (int s = 0; s < 4; ++s)
                    acc[mi][s] = __builtin_amdgcn_mfma_f32_16x16x32_bf16(a, bfrag[s][kk], acc[mi][s], 0, 0, 0);
            }
        }
#pragma unroll
        for (int mi = 0; mi < 2; ++mi)
#pragma unroll
            for (int s = 0; s < 4; ++s)
#pragma unroll
                for (int r = 0; r < 4; ++r) {
                    int o = (2 * g + mi) * 16 + lg * 4 + r;
                    ke[obase + (size_t)o * N_SP + s * 16 + lc] = f2bf(__expf(acc[mi][s][r]));
                }
    }
    // ---- v: mtiles 16..23 ----
#pragma unroll
    for (int g = 0; g < 4; ++g) {
        f32x4 acc[2][4] = {};
#pragma unroll
        for (int mi = 0; mi < 2; ++mi) {
            int row0 = (16 + 2 * g + mi) * 16;
#pragma unroll
            for (int kk = 0; kk < 2; ++kk) {
                int row = row0 + lc;
                int baddr = (row * 128 + (kk * 32 + lg * 8) * 2) ^ ((row & 7) << 4);
                bf16x8 a = *(const bf16x8*)((const char*)wl + baddr);
#pragma unroll
                for (int s = 0; s < 4; ++s)
                    acc[mi][s] = __builtin_amdgcn_mfma_f32_16x16x32_bf16(a, bfrag[s][kk], acc[mi][s], 0, 0, 0);
            }
        }
#pragma unroll
        for (int mi = 0; mi < 2; ++mi)
#pragma unroll
            for (int s = 0; s < 4; ++s)
#pragma unroll
                for (int r = 0; r < 4; ++r) {
                    int o = (2 * g + mi) * 16 + lg * 4 + r;
                    vv[obase + (size_t)o * N_SP + s * 16 + lc] = f2bf(acc[mi][s][r]);
                }
    }
}

// ====== K2: partial ctx[d][e] = sum_n ke[d,n]*vv[e,n]  (MFMA, 1 wave) ======
__global__ __launch_bounds__(64) void k2_ctx(const unsigned short* __restrict__ ke,
        const unsigned short* __restrict__ vv,
        float* __restrict__ ctx_part, float* __restrict__ ksum_part) {
    int blk = blockIdx.x;
    int bh = blk >> 6, ch = blk & 63;
    int b = bh >> 2, h = bh & 3;
    int l = threadIdx.x, lg = l >> 4, lc = l & 15;
    size_t base = (size_t)b * HID * N_SP + (size_t)h * DH * N_SP + (size_t)ch * CL2;
    f32x4 acc[2][2] = {};
    float ks0 = 0.f, ks1 = 0.f;
    for (int k0 = 0; k0 < CL2; k0 += 32) {
        bf16x8 af0 = *(const bf16x8*)(ke + base + (size_t)(lc) * N_SP + k0 + lg * 8);
        bf16x8 af1 = *(const bf16x8*)(ke + base + (size_t)(16 + lc) * N_SP + k0 + lg * 8);
        bf16x8 bf0 = *(const bf16x8*)(vv + base + (size_t)(lc) * N_SP + k0 + lg * 8);
        bf16x8 bf1 = *(const bf16x8*)(vv + base + (size_t)(16 + lc) * N_SP + k0 + lg * 8);
#pragma unroll
        for (int j = 0; j < 8; ++j) {
            ks0 += bf2f((unsigned short)af0[j]);
            ks1 += bf2f((unsigned short)af1[j]);
        }
        acc[0][0] = __builtin_amdgcn_mfma_f32_16x16x32_bf16(af0, bf0, acc[0][0], 0, 0, 0);
        acc[0][1] = __builtin_amdgcn_mfma_f32_16x16x32_bf16(af0, bf1, acc[0][1], 0, 0, 0);
        acc[1][0] = __builtin_amdgcn_mfma_f32_16x16x32_bf16(af1, bf0, acc[1][0], 0, 0, 0);
        acc[1][1] = __builtin_amdgcn_mfma_f32_16x16x32_bf16(af1, bf1, acc[1][1], 0, 0, 0);
    }
    ks0 += __shfl_xor(ks0, 16); ks0 += __shfl_xor(ks0, 32);
    ks1 += __shfl_xor(ks1, 16); ks1 += __shfl_xor(ks1, 32);
    float* cp = ctx_part + (size_t)blk * 1024;
#pragma unroll
    for (int di = 0; di < 2; ++di)
#pragma unroll
        for (int ei = 0; ei < 2; ++ei)
#pragma unroll
            for (int r = 0; r < 4; ++r)
                cp[(di * 16 + lg * 4 + r) * 32 + ei * 16 + lc] = acc[di][ei][r];
    if (l < 16) {
        ksum_part[blk * 32 + l] = ks0;
        ksum_part[blk * 32 + 16 + l] = ks1;
    }
}

// ============ K3: reduce partials, divide by k-softmax denominator ==========
__global__ __launch_bounds__(1024) void k3_ctx_reduce(const float* __restrict__ ctx_part,
        const float* __restrict__ ksum_part, float* __restrict__ ctx) {
    int bh = blockIdx.x, t = threadIdx.x;
    __shared__ float kst[DH];
    if (t < DH) {
        float s = 0.f;
        for (int ch = 0; ch < NCH2; ++ch) s += ksum_part[(bh * NCH2 + ch) * 32 + t];
        kst[t] = s;
    }
    __syncthreads();
    float s = 0.f;
    for (int ch = 0; ch < NCH2; ++ch) s += ctx_part[(size_t)(bh * NCH2 + ch) * 1024 + t];
    ctx[bh * 1024 + t] = s / kst[t >> 5];
}

// ====== Kw: Weff[b][o][h*32+d] = sum_e wout[o][h*32+e] * ctx[b,h][d][e] =====
__global__ __launch_bounds__(256) void kw_weff(const float* __restrict__ ctx,
        const float* __restrict__ wout, unsigned short* __restrict__ weff) {
    int b = blockIdx.x, t = threadIdx.x;
    __shared__ float cl[4096];
#pragma unroll
    for (int i = 0; i < 16; ++i) cl[t + i * 256] = ctx[b * 4096 + t + i * 256];
    __syncthreads();
    int o = t & 63, h = t >> 6;
    float wr[32];
#pragma unroll
    for (int e = 0; e < 32; ++e) wr[e] = wout[o * HID + h * 32 + e];
    for (int d = 0; d < 32; ++d) {
        float a = 0.f;
#pragma unroll
        for (int e = 0; e < 32; ++e) a = fmaf(wr[e], cl[h * 1024 + d * 32 + e], a);
        weff[b * 8192 + o * 128 + h * 32 + d] = f2bf(a);
    }
}

// ====== K4: y = Weff @ q + b  (MFMA), fused bias + GN stat partials =========
__global__ __launch_bounds__(256) void k4_out(const unsigned short* __restrict__ qs,
        const unsigned short* __restrict__ weff, const float* __restrict__ bout,
        unsigned short* __restrict__ y, float* __restrict__ part_stats) {
    __shared__ unsigned short wl[64 * 128];  // 16 KB bf16 swizzled
    __shared__ float red[8];
    int t = threadIdx.x;
    int wv = t >> 6, l = t & 63, lg = l >> 4, lc = l & 15;
    int p0 = blockIdx.x * 256 + wv * 64;
    int b = p0 >> 15, n0 = p0 & (N_SP - 1);
#pragma unroll
    for (int i = 0; i < 4; ++i) {
        int chunk = t + i * 256;            // 0..1023
        int row = chunk >> 4, c8 = (chunk & 15) * 8;
        u16x8 v = *(const u16x8*)(weff + (size_t)b * 8192 + row * 128 + c8);
        int baddr = (row * 256 + c8 * 2) ^ ((row & 7) << 4);
        *(u16x8*)((char*)wl + baddr) = v;
    }
    __syncthreads();

    const unsigned short* qb = qs + (size_t)b * HID * N_SP + n0;
    bf16x8 bfrag[4][4];
#pragma unroll
    for (int s = 0; s < 4; ++s)
#pragma unroll
        for (int kk = 0; kk < 4; ++kk) {
            bf16x8 v;
#pragma unroll
            for (int j = 0; j < 8; ++j)
                v[j] = (short)qb[(size_t)(kk * 32 + lg * 8 + j) * N_SP + s * 16 + lc];
            bfrag[s][kk] = v;
        }

    float s1 = 0.f, s2 = 0.f;
    size_t yb = (size_t)b * C_IN * N_SP + n0;
#pragma unroll
    for (int mt = 0; mt < 4; ++mt) {
        f32x4 acc[4] = {};
#pragma unroll
        for (int kk = 0; kk < 4; ++kk) {
            int row = mt * 16 + lc;
            int baddr = (row * 256 + (kk * 32 + lg * 8) * 2) ^ ((row & 7) << 4);
            bf16x8 a = *(const bf16x8*)((const char*)wl + baddr);
#pragma unroll
            for (int s = 0; s < 4; ++s)
                acc[s] = __builtin_amdgcn_mfma_f32_16x16x32_bf16(a, bfrag[s][kk], acc[s], 0, 0, 0);
        }
#pragma unroll
        for (int s = 0; s < 4; ++s)
#pragma unroll
            for (int r = 0; r < 4; ++r) {
                int o = mt * 16 + lg * 4 + r;
                float val = acc[s][r] + bout[o];
                y[yb + (size_t)o * N_SP + s * 16 + lc] = f2bf(val);
                s1 += val;
                s2 = fmaf(val, val, s2);
            }
    }
#pragma unroll
    for (int off = 32; off > 0; off >>= 1) {
        s1 += __shfl_down(s1, off, 64);
        s2 += __shfl_down(s2, off, 64);
    }
    if (l == 0) { red[wv * 2] = s1; red[wv * 2 + 1] = s2; }
    __syncthreads();
    if (t == 0) {
        part_stats[blockIdx.x * 2] = red[0] + red[2] + red[4] + red[6];
        part_stats[blockIdx.x * 2 + 1] = red[1] + red[3] + red[5] + red[7];
    }
}

// ================= K4b: per-batch stats reduce (deterministic) ==============
__global__ __launch_bounds__(128) void k4b_stats(const float* __restrict__ part_stats,
        float* __restrict__ stats) {
    int batch = blockIdx.x, t = threadIdx.x;
    float s = part_stats[(batch * 128 + t) * 2];
    float s2 = part_stats[(batch * 128 + t) * 2 + 1];
#pragma unroll
    for (int off = 32; off > 0; off >>= 1) {
        s += __shfl_down(s, off, 64);
        s2 += __shfl_down(s2, off, 64);
    }
    __shared__ float red[4];
    if ((t & 63) == 0) { red[(t >> 6) * 2] = s; red[(t >> 6) * 2 + 1] = s2; }
    __syncthreads();
    if (t == 0) {
        stats[batch * 2] = red[0] + red[2];
        stats[batch * 2 + 1] = red[1] + red[3];
    }
}

// =========================== K5: apply GroupNorm ============================
__global__ __launch_bounds__(256) void k5_gn(const unsigned short* __restrict__ y,
        const float* __restrict__ stats, const float* __restrict__ gnw,
        const float* __restrict__ gnb, float* __restrict__ out) {
    int gid = blockIdx.x * 256 + threadIdx.x;   // ushort8 index
    size_t base = (size_t)gid * 8;
    int b = (int)(base >> 21);
    int o = (int)((base >> 15) & 63);
    const float NGN = 64.f * 32768.f;
    float mean = stats[b * 2] / NGN;
    float var = stats[b * 2 + 1] / NGN - mean * mean;
    float inv = rsqrtf(var + GN_EPS_C);
    float w = gnw[o] * inv;
    float bb = gnb[o] - mean * inv * gnw[o];
    u16x8 v = *(const u16x8*)(y + base);
    float4 r0, r1;
    r0.x = fmaf(bf2f(v[0]), w, bb); r0.y = fmaf(bf2f(v[1]), w, bb);
    r0.z = fmaf(bf2f(v[2]), w, bb); r0.w = fmaf(bf2f(v[3]), w, bb);
    r1.x = fmaf(bf2f(v[4]), w, bb); r1.y = fmaf(bf2f(v[5]), w, bb);
    r1.z = fmaf(bf2f(v[6]), w, bb); r1.w = fmaf(bf2f(v[7]), w, bb);
    float4* op = (float4*)(out + base);
    op[0] = r0; op[1] = r1;
}

extern "C" void kernel_launch(void* const* d_in, const int* in_sizes, int n_in,
                              void* d_out, int out_size, void* d_ws, size_t ws_size,
                              hipStream_t stream) {
    const float* x    = (const float*)d_in[0];
    const float* wqkv = (const float*)d_in[1];
    const float* wout = (const float*)d_in[2];
    const float* bout = (const float*)d_in[3];
    const float* gnw  = (const float*)d_in[4];
    const float* gnb  = (const float*)d_in[5];
    float* out = (float*)d_out;

    char* ws = (char*)d_ws;
    const size_t QKV_B = (size_t)NB * HID * N_SP * 2;         // bytes per qkv tensor (16.8 MB)
    unsigned short* qs = (unsigned short*)(ws);
    unsigned short* ke = (unsigned short*)(ws + QKV_B);
    unsigned short* vv = (unsigned short*)(ws + 2 * QKV_B);
    size_t off = 3 * QKV_B;
    unsigned short* y = (unsigned short*)(ws + off); off += (size_t)NB * C_IN * N_SP * 2;  // 8.4 MB
    float* ctx_part  = (float*)(ws + off); off += (size_t)512 * 1024 * 4;                  // 2 MB
    float* ksum_part = (float*)(ws + off); off += (size_t)512 * 32 * 4;                    // 64 KB
    float* ctx       = (float*)(ws + off); off += 8192 * 4;                                // 32 KB
    unsigned short* weff = (unsigned short*)(ws + off); off += 2 * 8192 * 2;               // 32 KB
    float* part_stats = (float*)(ws + off); off += 256 * 2 * 4;
    float* stats      = (float*)(ws + off); off += 4 * 4;

    k1_qkv<<<dim3(256), dim3(256), 0, stream>>>(x, wqkv, qs, ke, vv);
    k2_ctx<<<dim3(NB * NHEADS * NCH2), dim3(64), 0, stream>>>(ke, vv, ctx_part, ksum_part);
    k3_ctx_reduce<<<dim3(NB * NHEADS), dim3(1024), 0, stream>>>(ctx_part, ksum_part, ctx);
    kw_weff<<<dim3(NB), dim3(256), 0, stream>>>(ctx, wout, weff);
    k4_out<<<dim3(256), dim3(256), 0, stream>>>(qs, weff, bout, y, part_stats);
    k4b_stats<<<dim3(NB), dim3(128), 0, stream>>>(part_stats, stats);
    k5_gn<<<dim3(2048), dim3(256), 0, stream>>>(y, stats, gnw, gnb, out);
}

// Round 4
// 62.384 us; speedup vs baseline: 5.8615x; 1.0457x over previous
//
#include <hip/hip_runtime.h>
#include <hip/hip_bf16.h>

#define NB 2
#define C_IN 64
#define N_SP 32768
#define NHEADS 4
#define DH 32
#define HID 128
#define QK_SCALE 0.17677669529663687f  // 32^-0.5
#define GN_EPS_C 1e-5f

using bf16x8 = __attribute__((ext_vector_type(8))) short;
using f32x4  = __attribute__((ext_vector_type(4))) float;
using u16x4  = __attribute__((ext_vector_type(4))) unsigned short;

__device__ __forceinline__ unsigned short f2bf(float f) {
    union { float f; unsigned u; } c{f};
    unsigned r = c.u + 0x7FFFu + ((c.u >> 16) & 1u);   // RNE
    return (unsigned short)(r >> 16);
}
__device__ __forceinline__ float bf2f(unsigned short u) {
    union { unsigned u; float f; } c{ (unsigned)u << 16 };
    return c.f;
}

// ---- prep: wqkv fp32 [384][64] -> bf16 MFMA A-fragment layout --------------
// wfrag[f=mt*2+kk][lane][8]: lane(lg,lc) holds w[mt*16+lc][kk*32+lg*8 .. +8]
__global__ __launch_bounds__(256) void kprep(const float* __restrict__ wqkv,
        unsigned short* __restrict__ wfrag) {
    int t = threadIdx.x;
#pragma unroll
    for (int i = 0; i < 12; ++i) {
        int idx = t + i * 256;          // 0..3071 = (frag, lane)
        int f = idx >> 6, lane = idx & 63;
        int mt = f >> 1, kk = f & 1;
        int row = mt * 16 + (lane & 15);
        int c0 = kk * 32 + (lane >> 4) * 8;
        const float* wp = wqkv + row * 64 + c0;
        unsigned short* op = wfrag + (size_t)idx * 8;
#pragma unroll
        for (int j = 0; j < 8; ++j) op[j] = f2bf(wp[j]);
    }
}

// ==== KA: per-block qkv; k/v -> ctx partial (LDS only); q-softmax -> frags ==
__global__ __launch_bounds__(256) void kA(const float* __restrict__ x,
        const unsigned short* __restrict__ wfrag,
        unsigned short* __restrict__ qs_frag,
        float* __restrict__ ctx_part, float* __restrict__ ksum_part) {
    __shared__ unsigned short kt[8192];   // [32][256] bf16, XOR-swizzled
    __shared__ unsigned short vt[8192];
    const int t = threadIdx.x, wv = t >> 6, l = t & 63, lg = l >> 4, lc = l & 15;
    const int blk = blockIdx.x;
    const int b = blk >> 7, nblk = blk & 127;
    const int n0 = nblk * 256 + wv * 64;

    // x fragments (B-operand): lane holds x[kk*32+lg*8+j][n0+s*16+lc]
    const float* xb = x + (size_t)b * C_IN * N_SP;
    bf16x8 xf[4][2];
#pragma unroll
    for (int s = 0; s < 4; ++s) {
        int n = n0 + s * 16 + lc;
#pragma unroll
        for (int kk = 0; kk < 2; ++kk) {
            bf16x8 v;
#pragma unroll
            for (int j = 0; j < 8; ++j)
                v[j] = (short)f2bf(xb[(size_t)(kk * 32 + lg * 8 + j) * N_SP + n]);
            xf[s][kk] = v;
        }
    }

    const int di = wv >> 1, ei = wv & 1;
#pragma unroll
    for (int h = 0; h < NHEADS; ++h) {
        f32x4 ka[2][4] = {}, va[2][4] = {};
#pragma unroll
        for (int mi = 0; mi < 2; ++mi)
#pragma unroll
            for (int kk = 0; kk < 2; ++kk) {
                bf16x8 ak = *(const bf16x8*)(wfrag + ((size_t)((8 + 2 * h + mi) * 2 + kk) * 64 + l) * 8);
                bf16x8 av = *(const bf16x8*)(wfrag + ((size_t)((16 + 2 * h + mi) * 2 + kk) * 64 + l) * 8);
#pragma unroll
                for (int s = 0; s < 4; ++s) {
                    ka[mi][s] = __builtin_amdgcn_mfma_f32_16x16x32_bf16(ak, xf[s][kk], ka[mi][s], 0, 0, 0);
                    va[mi][s] = __builtin_amdgcn_mfma_f32_16x16x32_bf16(av, xf[s][kk], va[mi][s], 0, 0, 0);
                }
            }
        __syncthreads();   // previous head's kt/vt reads complete
#pragma unroll
        for (int mi = 0; mi < 2; ++mi)
#pragma unroll
            for (int s = 0; s < 4; ++s)
#pragma unroll
                for (int r = 0; r < 4; ++r) {
                    int row = mi * 16 + lg * 4 + r;
                    int col = wv * 64 + s * 16 + lc;
                    int swz = (row & 7) << 4;
                    *(unsigned short*)((char*)kt + ((row * 512 + col * 2) ^ swz)) = f2bf(__expf(ka[mi][s][r]));
                    *(unsigned short*)((char*)vt + ((row * 512 + col * 2) ^ swz)) = f2bf(va[mi][s][r]);
                }
        __syncthreads();
        // ctx tile (di, ei): contract over the block's 256 positions
        f32x4 ca = {};
        float ks = 0.f;
#pragma unroll
        for (int k0 = 0; k0 < 256; k0 += 32) {
            int arow = di * 16 + lc, brow = ei * 16 + lc;
            bf16x8 af = *(const bf16x8*)((const char*)kt + ((arow * 512 + (k0 + lg * 8) * 2) ^ ((arow & 7) << 4)));
            bf16x8 bf = *(const bf16x8*)((const char*)vt + ((brow * 512 + (k0 + lg * 8) * 2) ^ ((brow & 7) << 4)));
            if (ei == 0) {
#pragma unroll
                for (int j = 0; j < 8; ++j) ks += bf2f((unsigned short)af[j]);
            }
            ca = __builtin_amdgcn_mfma_f32_16x16x32_bf16(af, bf, ca, 0, 0, 0);
        }
        float* cp = ctx_part + ((size_t)blk * 4 + h) * 1024;
#pragma unroll
        for (int r = 0; r < 4; ++r)
            cp[(di * 16 + lg * 4 + r) * 32 + ei * 16 + lc] = ca[r];
        if (ei == 0) {
            ks += __shfl_xor(ks, 16);
            ks += __shfl_xor(ks, 32);
            if (lg == 0) ksum_part[((size_t)blk * 4 + h) * 32 + di * 16 + lc] = ks;
        }
    }

    // ---- q heads: softmax over 32 channels, store in MFMA B-frag layout ----
#pragma unroll
    for (int h = 0; h < NHEADS; ++h) {
        f32x4 qa[2][4] = {};
#pragma unroll
        for (int mi = 0; mi < 2; ++mi)
#pragma unroll
            for (int kk = 0; kk < 2; ++kk) {
                bf16x8 aq = *(const bf16x8*)(wfrag + ((size_t)((2 * h + mi) * 2 + kk) * 64 + l) * 8);
#pragma unroll
                for (int s = 0; s < 4; ++s)
                    qa[mi][s] = __builtin_amdgcn_mfma_f32_16x16x32_bf16(aq, xf[s][kk], qa[mi][s], 0, 0, 0);
            }
#pragma unroll
        for (int s = 0; s < 4; ++s) {
            float m = -1e30f;
#pragma unroll
            for (int mi = 0; mi < 2; ++mi)
#pragma unroll
                for (int r = 0; r < 4; ++r) m = fmaxf(m, qa[mi][s][r]);
            m = fmaxf(m, __shfl_xor(m, 16));
            m = fmaxf(m, __shfl_xor(m, 32));
            float sum = 0.f;
#pragma unroll
            for (int mi = 0; mi < 2; ++mi)
#pragma unroll
                for (int r = 0; r < 4; ++r) {
                    float e = __expf(qa[mi][s][r] - m);
                    qa[mi][s][r] = e; sum += e;
                }
            sum += __shfl_xor(sum, 16);
            sum += __shfl_xor(sum, 32);
            float inv = QK_SCALE / sum;
            // frag(b, nblk, wv, s, kk=h): lane' = (mi*2+(lg>>1))*16+lc, j0=(lg&1)*4
            size_t fb = ((((size_t)(b * 128 + nblk) * 4 + wv) * 4 + s) * 4 + h) * 512;
#pragma unroll
            for (int mi = 0; mi < 2; ++mi) {
                u16x4 pk;
#pragma unroll
                for (int r = 0; r < 4; ++r) pk[r] = f2bf(qa[mi][s][r] * inv);
                *(u16x4*)(qs_frag + fb + (size_t)((mi * 2 + (lg >> 1)) * 16 + lc) * 8 + (lg & 1) * 4) = pk;
            }
        }
    }
}

// ======= KB: reduce ctx partials; Weff = wout · (ctx/ksum)  (8 blocks) ======
__global__ __launch_bounds__(256) void kB(const float* __restrict__ ctx_part,
        const float* __restrict__ ksum_part, const float* __restrict__ wout,
        unsigned short* __restrict__ weff) {
    __shared__ float cred[1024];
    __shared__ float ksl[32];
    int blk = blockIdx.x, t = threadIdx.x;
    int bb = blk >> 2, h = blk & 3;
    float accs[4] = {0.f, 0.f, 0.f, 0.f};
    for (int i = 0; i < 128; ++i) {
        const float* cp = ctx_part + ((size_t)((bb * 128 + i) * 4 + h)) * 1024;
#pragma unroll
        for (int j = 0; j < 4; ++j) accs[j] += cp[t + j * 256];
    }
#pragma unroll
    for (int j = 0; j < 4; ++j) cred[t + j * 256] = accs[j];
    if (t < 32) {
        float s = 0.f;
        for (int i = 0; i < 128; ++i)
            s += ksum_part[((size_t)((bb * 128 + i) * 4 + h)) * 32 + t];
        ksl[t] = s;
    }
    __syncthreads();
#pragma unroll
    for (int i = 0; i < 8; ++i) {
        int oi = t * 8 + i;
        int o = oi >> 5, d = oi & 31;
        const float* wrow = wout + o * HID + h * 32;
        const float* crow = cred + d * 32;
        float a = 0.f;
#pragma unroll
        for (int e = 0; e < 32; ++e) a = fmaf(wrow[e], crow[e], a);
        a /= ksl[d];
        weff[((size_t)bb * 64 + o) * 128 + h * 32 + d] = f2bf(a);
    }
}

// ======= KC: y = Weff·q + b (MFMA, not stored) -> GN stat partials ==========
__global__ __launch_bounds__(256) void kC(const unsigned short* __restrict__ qs_frag,
        const unsigned short* __restrict__ weff, const float* __restrict__ bout,
        float* __restrict__ pstats) {
    __shared__ float red[8];
    const int t = threadIdx.x, wv = t >> 6, l = t & 63, lg = l >> 4, lc = l & 15;
    const int blk = blockIdx.x;
    const int b = blk >> 7, nblk = blk & 127;
    const unsigned short* wb = weff + (size_t)b * 8192;
    f32x4 acc[4][4] = {};
#pragma unroll
    for (int kk = 0; kk < 4; ++kk) {
        bf16x8 bq[4];
#pragma unroll
        for (int s = 0; s < 4; ++s)
            bq[s] = *(const bf16x8*)(qs_frag +
                ((((size_t)(b * 128 + nblk) * 4 + wv) * 4 + s) * 4 + kk) * 512 + (size_t)l * 8);
#pragma unroll
        for (int mt = 0; mt < 4; ++mt) {
            bf16x8 af = *(const bf16x8*)(wb + (size_t)(mt * 16 + lc) * 128 + kk * 32 + lg * 8);
#pragma unroll
            for (int s = 0; s < 4; ++s)
                acc[mt][s] = __builtin_amdgcn_mfma_f32_16x16x32_bf16(af, bq[s], acc[mt][s], 0, 0, 0);
        }
    }
    float s1 = 0.f, s2 = 0.f;
#pragma unroll
    for (int mt = 0; mt < 4; ++mt) {
#pragma unroll
        for (int r = 0; r < 4; ++r) {
            float bo = bout[mt * 16 + lg * 4 + r];
#pragma unroll
            for (int s = 0; s < 4; ++s) {
                float yv = acc[mt][s][r] + bo;
                s1 += yv;
                s2 = fmaf(yv, yv, s2);
            }
        }
    }
#pragma unroll
    for (int off = 32; off > 0; off >>= 1) {
        s1 += __shfl_down(s1, off, 64);
        s2 += __shfl_down(s2, off, 64);
    }
    if (l == 0) { red[wv * 2] = s1; red[wv * 2 + 1] = s2; }
    __syncthreads();
    if (t == 0) {
        pstats[blk * 2]     = red[0] + red[2] + red[4] + red[6];
        pstats[blk * 2 + 1] = red[1] + red[3] + red[5] + red[7];
    }
}

// ================= KD: finalize per-batch mean / inv-std ====================
__global__ __launch_bounds__(128) void kD(const float* __restrict__ pstats,
        float* __restrict__ stats) {
    int batch = blockIdx.x, t = threadIdx.x;
    float s  = pstats[(batch * 128 + t) * 2];
    float s2 = pstats[(batch * 128 + t) * 2 + 1];
#pragma unroll
    for (int off = 32; off > 0; off >>= 1) {
        s  += __shfl_down(s, off, 64);
        s2 += __shfl_down(s2, off, 64);
    }
    __shared__ float red[4];
    if ((t & 63) == 0) { red[(t >> 6) * 2] = s; red[(t >> 6) * 2 + 1] = s2; }
    __syncthreads();
    if (t == 0) {
        const float N = 64.f * 32768.f;
        float mean = (red[0] + red[2]) / N;
        float var  = (red[1] + red[3]) / N - mean * mean;
        stats[batch * 2]     = mean;
        stats[batch * 2 + 1] = rsqrtf(var + GN_EPS_C);
    }
}

// ========== KE: recompute y, apply GroupNorm affine, write out ==============
__global__ __launch_bounds__(256) void kE(const unsigned short* __restrict__ qs_frag,
        const unsigned short* __restrict__ weff, const float* __restrict__ bout,
        const float* __restrict__ stats, const float* __restrict__ gnw,
        const float* __restrict__ gnb, float* __restrict__ out) {
    const int t = threadIdx.x, wv = t >> 6, l = t & 63, lg = l >> 4, lc = l & 15;
    const int blk = blockIdx.x;
    const int b = blk >> 7, nblk = blk & 127;
    const int n0 = nblk * 256 + wv * 64;
    const unsigned short* wb = weff + (size_t)b * 8192;
    f32x4 acc[4][4] = {};
#pragma unroll
    for (int kk = 0; kk < 4; ++kk) {
        bf16x8 bq[4];
#pragma unroll
        for (int s = 0; s < 4; ++s)
            bq[s] = *(const bf16x8*)(qs_frag +
                ((((size_t)(b * 128 + nblk) * 4 + wv) * 4 + s) * 4 + kk) * 512 + (size_t)l * 8);
#pragma unroll
        for (int mt = 0; mt < 4; ++mt) {
            bf16x8 af = *(const bf16x8*)(wb + (size_t)(mt * 16 + lc) * 128 + kk * 32 + lg * 8);
#pragma unroll
            for (int s = 0; s < 4; ++s)
                acc[mt][s] = __builtin_amdgcn_mfma_f32_16x16x32_bf16(af, bq[s], acc[mt][s], 0, 0, 0);
        }
    }
    float mean = stats[b * 2], inv = stats[b * 2 + 1];
    float* ob = out + (size_t)b * C_IN * N_SP;
#pragma unroll
    for (int mt = 0; mt < 4; ++mt)
#pragma unroll
        for (int r = 0; r < 4; ++r) {
            int o = mt * 16 + lg * 4 + r;
            float w2 = gnw[o] * inv;
            float b2 = (bout[o] - mean) * w2 + gnb[o];
#pragma unroll
            for (int s = 0; s < 4; ++s)
                ob[(size_t)o * N_SP + n0 + s * 16 + lc] = fmaf(acc[mt][s][r], w2, b2);
        }
}

extern "C" void kernel_launch(void* const* d_in, const int* in_sizes, int n_in,
                              void* d_out, int out_size, void* d_ws, size_t ws_size,
                              hipStream_t stream) {
    const float* x    = (const float*)d_in[0];
    const float* wqkv = (const float*)d_in[1];
    const float* wout = (const float*)d_in[2];
    const float* bout = (const float*)d_in[3];
    const float* gnw  = (const float*)d_in[4];
    const float* gnb  = (const float*)d_in[5];
    float* out = (float*)d_out;

    char* ws = (char*)d_ws;
    size_t off = 0;
    unsigned short* wfrag = (unsigned short*)(ws + off); off += 49152;            // 48 KB
    unsigned short* qs_frag = (unsigned short*)(ws + off); off += 16777216;       // 16 MB
    float* ctx_part  = (float*)(ws + off); off += 4194304;                        // 4 MB
    float* ksum_part = (float*)(ws + off); off += 131072;                         // 128 KB
    unsigned short* weff = (unsigned short*)(ws + off); off += 32768;             // 32 KB
    float* pstats = (float*)(ws + off); off += 2048;
    float* stats  = (float*)(ws + off); off += 64;

    kprep<<<dim3(1), dim3(256), 0, stream>>>(wqkv, wfrag);
    kA<<<dim3(256), dim3(256), 0, stream>>>(x, wfrag, qs_frag, ctx_part, ksum_part);
    kB<<<dim3(8), dim3(256), 0, stream>>>(ctx_part, ksum_part, wout, weff);
    kC<<<dim3(256), dim3(256), 0, stream>>>(qs_frag, weff, bout, pstats);
    kD<<<dim3(NB), dim3(128), 0, stream>>>(pstats, stats);
    kE<<<dim3(256), dim3(256), 0, stream>>>(qs_frag, weff, bout, stats, gnw, gnb, out);
}

// Round 5
// 50.336 us; speedup vs baseline: 7.2644x; 1.2394x over previous
//
#include <hip/hip_runtime.h>
#include <hip/hip_bf16.h>

#define NB 2
#define C_IN 64
#define N_SP 32768
#define NHEADS 4
#define DH 32
#define HID 128
#define QK_SCALE 0.17677669529663687f  // 32^-0.5
#define GN_EPS_C 1e-5f
#define NGN 2097152.0f                  // 64*32768

using bf16x8 = __attribute__((ext_vector_type(8))) short;
using f32x4  = __attribute__((ext_vector_type(4))) float;
using u16x4  = __attribute__((ext_vector_type(4))) unsigned short;
using u16x8  = __attribute__((ext_vector_type(8))) unsigned short;

__device__ __forceinline__ unsigned short f2bf(float f) {
    union { float f; unsigned u; } c{f};
    unsigned r = c.u + 0x7FFFu + ((c.u >> 16) & 1u);   // RNE
    return (unsigned short)(r >> 16);
}
__device__ __forceinline__ float bf2f(unsigned short u) {
    union { unsigned u; float f; } c{ (unsigned)u << 16 };
    return c.f;
}

// load the wave's x fragments: lane holds x[kk*32+lg*8+j][n0+s*16+lc]
__device__ __forceinline__ void load_xf(const float* __restrict__ xb, int n0,
        int lg, int lc, bf16x8 xf[4][2]) {
#pragma unroll
    for (int s = 0; s < 4; ++s) {
        int n = n0 + s * 16 + lc;
#pragma unroll
        for (int kk = 0; kk < 2; ++kk) {
            bf16x8 v;
#pragma unroll
            for (int j = 0; j < 8; ++j)
                v[j] = (short)f2bf(xb[(size_t)(kk * 32 + lg * 8 + j) * N_SP + n]);
            xf[s][kk] = v;
        }
    }
}

// ==== kA: k/v per block (swapped-operand MFMA), ctx partials. No q. =========
__global__ __launch_bounds__(256) void kA(const float* __restrict__ x,
        const float* __restrict__ wqkv,
        float* __restrict__ ctx_part, float* __restrict__ ksum_part) {
    __shared__ unsigned short kt[8192];   // [ch 32][pos 256] bf16, XOR-swizzled
    __shared__ unsigned short vt[8192];
    const int t = threadIdx.x, wv = t >> 6, l = t & 63, lg = l >> 4, lc = l & 15;
    const int blk = blockIdx.x;
    const int b = blk >> 7, nblk = blk & 127;
    const int n0 = nblk * 256 + wv * 64;

    bf16x8 xf[4][2];
    load_xf(x + (size_t)b * C_IN * N_SP, n0, lg, lc, xf);

    const int di = wv >> 1, ei = wv & 1;
#pragma unroll
    for (int h = 0; h < NHEADS; ++h) {
        f32x4 ka[4][2] = {}, va[4][2] = {};   // [s][e]
#pragma unroll
        for (int e = 0; e < 2; ++e)
#pragma unroll
            for (int kk = 0; kk < 2; ++kk) {
                const float* pk = wqkv + (size_t)(HID + h * 32 + e * 16 + lc) * 64 + kk * 32 + lg * 8;
                const float* pv = wqkv + (size_t)(2 * HID + h * 32 + e * 16 + lc) * 64 + kk * 32 + lg * 8;
                bf16x8 wk, wf;
#pragma unroll
                for (int j = 0; j < 8; ++j) { wk[j] = (short)f2bf(pk[j]); wf[j] = (short)f2bf(pv[j]); }
#pragma unroll
                for (int s = 0; s < 4; ++s) {
                    ka[s][e] = __builtin_amdgcn_mfma_f32_16x16x32_bf16(xf[s][kk], wk, ka[s][e], 0, 0, 0);
                    va[s][e] = __builtin_amdgcn_mfma_f32_16x16x32_bf16(xf[s][kk], wf, va[s][e], 0, 0, 0);
                }
            }
        __syncthreads();   // previous head's kt/vt reads complete
        // D layout: row = pos-local (lg*4+r), col = ch-local (lc)
#pragma unroll
        for (int s = 0; s < 4; ++s)
#pragma unroll
            for (int e = 0; e < 2; ++e) {
                u16x4 pk, pv;
#pragma unroll
                for (int r = 0; r < 4; ++r) {
                    pk[r] = f2bf(__expf(ka[s][e][r]));
                    pv[r] = f2bf(va[s][e][r]);
                }
                int ch = e * 16 + lc;
                int pos = wv * 64 + s * 16 + lg * 4;
                int ba = (ch * 512 + pos * 2) ^ ((ch & 7) << 4);
                *(u16x4*)((char*)kt + ba) = pk;
                *(u16x4*)((char*)vt + ba) = pv;
            }
        __syncthreads();
        // ctx tile (di, ei): contract over the block's 256 positions
        f32x4 ca = {};
        float ks = 0.f;
#pragma unroll
        for (int k0 = 0; k0 < 256; k0 += 32) {
            int ar = di * 16 + lc, br = ei * 16 + lc;
            bf16x8 af = *(const bf16x8*)((const char*)kt + ((ar * 512 + (k0 + lg * 8) * 2) ^ ((ar & 7) << 4)));
            bf16x8 bf = *(const bf16x8*)((const char*)vt + ((br * 512 + (k0 + lg * 8) * 2) ^ ((br & 7) << 4)));
            if (ei == 0) {
#pragma unroll
                for (int j = 0; j < 8; ++j) ks += bf2f((unsigned short)af[j]);
            }
            ca = __builtin_amdgcn_mfma_f32_16x16x32_bf16(af, bf, ca, 0, 0, 0);
        }
        float* cp = ctx_part + ((size_t)(b * 4 + h) * 128 + nblk) * 1024;
#pragma unroll
        for (int r = 0; r < 4; ++r)
            cp[(di * 16 + lg * 4 + r) * 32 + ei * 16 + lc] = ca[r];
        if (ei == 0) {
            ks += __shfl_xor(ks, 16);
            ks += __shfl_xor(ks, 32);
            if (lg == 0)
                ksum_part[((size_t)(b * 4 + h) * 128 + nblk) * 32 + di * 16 + lc] = ks;
        }
    }
}

// ==== kB: reduce ctx/ksum partials, Weff = wout·(ctx/ksum)  (64 blocks) =====
__global__ __launch_bounds__(256) void kB(const float* __restrict__ ctx_part,
        const float* __restrict__ ksum_part, const float* __restrict__ wout,
        unsigned short* __restrict__ weff) {
    __shared__ float cred2[2][128];
    __shared__ float cred[128];          // [4 d][32 e]
    __shared__ float ks2[4][32];
    __shared__ float ksl[4];
    const int blk = blockIdx.x;
    const int g = blk >> 3, ds = blk & 7;     // g = b*4+h; ds: 4-d slice
    const int bb = g >> 2, h = g & 3;
    const int t = threadIdx.x;
    const int tt = t & 127, th = t >> 7;
    float a = 0.f;
    const float* cp = ctx_part + ((size_t)g * 128 + th * 64) * 1024 + ds * 128 + tt;
#pragma unroll 8
    for (int i = 0; i < 64; ++i) a += cp[(size_t)i * 1024];
    cred2[th][tt] = a;
    if (t < 128) {
        int dl = t >> 5, ic = t & 31;
        float s = 0.f;
        const float* kp = ksum_part + ((size_t)g * 128 + ic * 4) * 32 + ds * 4 + dl;
#pragma unroll
        for (int i = 0; i < 4; ++i) s += kp[i * 32];
        ks2[dl][ic] = s;
    }
    __syncthreads();
    if (t < 128) cred[t] = cred2[0][t] + cred2[1][t];
    if (t < 4) {
        float s = 0.f;
#pragma unroll
        for (int i = 0; i < 32; ++i) s += ks2[t][i];
        ksl[t] = s;
    }
    __syncthreads();
    const int o = t >> 2, dl = t & 3;
    const float* wrow = wout + o * HID + h * 32;
    const float* crow = cred + dl * 32;
    float acc = 0.f;
#pragma unroll
    for (int e = 0; e < 32; ++e) acc = fmaf(wrow[e], crow[e], acc);
    acc /= ksl[dl];
    weff[((size_t)bb * 64 + o) * 128 + h * 32 + ds * 4 + dl] = f2bf(acc);
}

// ==== kC: q from x, softmax, y = Weff·q̂ (MFMA), stats, store y_t bf16 ======
__global__ __launch_bounds__(256) void kC(const float* __restrict__ x,
        const float* __restrict__ wqkv, const unsigned short* __restrict__ weff,
        const float* __restrict__ bout, unsigned short* __restrict__ y_t,
        float* __restrict__ pstats) {
    __shared__ unsigned short qt[256 * 128];  // [pos 256][ch 128] swizzled (64 KB)
    __shared__ float red[8];
    const int t = threadIdx.x, wv = t >> 6, l = t & 63, lg = l >> 4, lc = l & 15;
    const int blk = blockIdx.x;
    const int b = blk >> 7, nblk = blk & 127;
    const int n0 = nblk * 256 + wv * 64;

    bf16x8 xf[4][2];
    load_xf(x + (size_t)b * C_IN * N_SP, n0, lg, lc, xf);

    // q heads (A = w, B = x): D col = pos(lc), rows = q-ch
#pragma unroll
    for (int h = 0; h < NHEADS; ++h) {
        f32x4 qa[2][4] = {};
#pragma unroll
        for (int mi = 0; mi < 2; ++mi)
#pragma unroll
            for (int kk = 0; kk < 2; ++kk) {
                const float* pq = wqkv + (size_t)((h * 2 + mi) * 16 + lc) * 64 + kk * 32 + lg * 8;
                bf16x8 aq;
#pragma unroll
                for (int j = 0; j < 8; ++j) aq[j] = (short)f2bf(pq[j]);
#pragma unroll
                for (int s = 0; s < 4; ++s)
                    qa[mi][s] = __builtin_amdgcn_mfma_f32_16x16x32_bf16(aq, xf[s][kk], qa[mi][s], 0, 0, 0);
            }
#pragma unroll
        for (int s = 0; s < 4; ++s) {
            float m = -1e30f;
#pragma unroll
            for (int mi = 0; mi < 2; ++mi)
#pragma unroll
                for (int r = 0; r < 4; ++r) m = fmaxf(m, qa[mi][s][r]);
            m = fmaxf(m, __shfl_xor(m, 16));
            m = fmaxf(m, __shfl_xor(m, 32));
            float sum = 0.f;
#pragma unroll
            for (int mi = 0; mi < 2; ++mi)
#pragma unroll
                for (int r = 0; r < 4; ++r) {
                    float e = __expf(qa[mi][s][r] - m);
                    qa[mi][s][r] = e; sum += e;
                }
            sum += __shfl_xor(sum, 16);
            sum += __shfl_xor(sum, 32);
            float inv = QK_SCALE / sum;
            int pos = wv * 64 + s * 16 + lc;
            int swz = (pos & 7) << 4;
#pragma unroll
            for (int mi = 0; mi < 2; ++mi) {
                u16x4 pk;
#pragma unroll
                for (int r = 0; r < 4; ++r) pk[r] = f2bf(qa[mi][s][r] * inv);
                int ch0 = h * 32 + mi * 16 + lg * 4;
                *(u16x4*)((char*)qt + ((pos * 256 + ch0 * 2) ^ swz)) = pk;
            }
        }
    }
    // no __syncthreads needed: each wave reads only its own pos rows

    // y = Weff·q̂ : A = Weff[out-ch][q-ch], B = qt[q-ch][pos]
    f32x4 acc[4][4] = {};   // [mt][s]
    const unsigned short* wb = weff + (size_t)b * 8192;
#pragma unroll
    for (int kk = 0; kk < 4; ++kk) {
        bf16x8 bq[4];
#pragma unroll
        for (int s = 0; s < 4; ++s) {
            int pos = wv * 64 + s * 16 + lc;
            bq[s] = *(const bf16x8*)((const char*)qt +
                ((pos * 256 + (kk * 32 + lg * 8) * 2) ^ ((pos & 7) << 4)));
        }
#pragma unroll
        for (int mt = 0; mt < 4; ++mt) {
            bf16x8 af = *(const bf16x8*)(wb + (size_t)(mt * 16 + lc) * 128 + kk * 32 + lg * 8);
#pragma unroll
            for (int s = 0; s < 4; ++s)
                acc[mt][s] = __builtin_amdgcn_mfma_f32_16x16x32_bf16(af, bq[s], acc[mt][s], 0, 0, 0);
        }
    }
    // bias + stats + y_t store ([n][o] bf16, b64 stores)
    float s1 = 0.f, s2 = 0.f;
#pragma unroll
    for (int mt = 0; mt < 4; ++mt) {
        float bo[4];
#pragma unroll
        for (int r = 0; r < 4; ++r) bo[r] = bout[mt * 16 + lg * 4 + r];
#pragma unroll
        for (int s = 0; s < 4; ++s) {
            u16x4 pk;
#pragma unroll
            for (int r = 0; r < 4; ++r) {
                float val = acc[mt][s][r] + bo[r];
                s1 += val;
                s2 = fmaf(val, val, s2);
                pk[r] = f2bf(val);
            }
            int n = nblk * 256 + wv * 64 + s * 16 + lc;
            *(u16x4*)(y_t + ((size_t)b * N_SP + n) * 64 + mt * 16 + lg * 4) = pk;
        }
    }
#pragma unroll
    for (int off = 32; off > 0; off >>= 1) {
        s1 += __shfl_down(s1, off, 64);
        s2 += __shfl_down(s2, off, 64);
    }
    if (l == 0) { red[wv * 2] = s1; red[wv * 2 + 1] = s2; }
    __syncthreads();
    if (t == 0) {
        pstats[blk * 2]     = red[0] + red[2] + red[4] + red[6];
        pstats[blk * 2 + 1] = red[1] + red[3] + red[5] + red[7];
    }
}

// ==== kE: inline stats reduce, GN affine, y_t[n][o] -> out[o][n] ============
__global__ __launch_bounds__(256) void kE(const unsigned short* __restrict__ y_t,
        const float* __restrict__ pstats, const float* __restrict__ gnw,
        const float* __restrict__ gnb, float* __restrict__ out) {
    __shared__ float pr[4];
    __shared__ float ms[2];
    __shared__ float w2s[64], b2s[64];
    const int t = threadIdx.x;
    const int blk = blockIdx.x;
    const int b = blk >> 9, nb = blk & 511;
    // reduce this batch's 128 stat pairs (redundant per block, L2-hot)
    float s1 = 0.f, s2 = 0.f;
    if (t < 128) {
        s1 = pstats[(b * 128 + t) * 2];
        s2 = pstats[(b * 128 + t) * 2 + 1];
    }
#pragma unroll
    for (int off = 32; off > 0; off >>= 1) {
        s1 += __shfl_down(s1, off, 64);
        s2 += __shfl_down(s2, off, 64);
    }
    if (t < 128 && (t & 63) == 0) { pr[(t >> 6) * 2] = s1; pr[(t >> 6) * 2 + 1] = s2; }
    __syncthreads();
    if (t == 0) {
        float S1 = pr[0] + pr[2], S2 = pr[1] + pr[3];
        float mean = S1 / NGN;
        float var = S2 / NGN - mean * mean;
        ms[0] = mean; ms[1] = rsqrtf(var + GN_EPS_C);
    }
    __syncthreads();
    if (t < 64) {
        float w2 = gnw[t] * ms[1];
        w2s[t] = w2;
        b2s[t] = gnb[t] - ms[0] * w2;
    }
    __syncthreads();
    const int n = nb * 64 + (t >> 2), o0 = (t & 3) * 16;
    const unsigned short* yp = y_t + ((size_t)b * N_SP + n) * 64 + o0;
    u16x8 v0 = *(const u16x8*)yp;
    u16x8 v1 = *(const u16x8*)(yp + 8);
    float* ob = out + (size_t)b * C_IN * N_SP + n;
#pragma unroll
    for (int j = 0; j < 8; ++j)
        ob[(size_t)(o0 + j) * N_SP] = fmaf(bf2f((unsigned short)v0[j]), w2s[o0 + j], b2s[o0 + j]);
#pragma unroll
    for (int j = 0; j < 8; ++j)
        ob[(size_t)(o0 + 8 + j) * N_SP] = fmaf(bf2f((unsigned short)v1[j]), w2s[o0 + 8 + j], b2s[o0 + 8 + j]);
}

extern "C" void kernel_launch(void* const* d_in, const int* in_sizes, int n_in,
                              void* d_out, int out_size, void* d_ws, size_t ws_size,
                              hipStream_t stream) {
    const float* x    = (const float*)d_in[0];
    const float* wqkv = (const float*)d_in[1];
    const float* wout = (const float*)d_in[2];
    const float* bout = (const float*)d_in[3];
    const float* gnw  = (const float*)d_in[4];
    const float* gnb  = (const float*)d_in[5];
    float* out = (float*)d_out;

    char* ws = (char*)d_ws;
    size_t off = 0;
    float* ctx_part  = (float*)(ws + off); off += (size_t)8 * 128 * 1024 * 4;  // 4 MB
    float* ksum_part = (float*)(ws + off); off += (size_t)8 * 128 * 32 * 4;    // 128 KB
    unsigned short* weff = (unsigned short*)(ws + off); off += 2 * 8192 * 2;   // 32 KB
    unsigned short* y_t  = (unsigned short*)(ws + off); off += (size_t)NB * N_SP * 64 * 2;  // 8 MB
    float* pstats = (float*)(ws + off); off += 256 * 2 * 4;

    kA<<<dim3(256), dim3(256), 0, stream>>>(x, wqkv, ctx_part, ksum_part);
    kB<<<dim3(64), dim3(256), 0, stream>>>(ctx_part, ksum_part, wout, weff);
    kC<<<dim3(256), dim3(256), 0, stream>>>(x, wqkv, weff, bout, y_t, pstats);
    kE<<<dim3(1024), dim3(256), 0, stream>>>(y_t, pstats, gnw, gnb, out);
}